// Round 2
// baseline (31127.505 us; speedup 1.0000x reference)
//
#include <hip/hip_runtime.h>
#include <hip/hip_bf16.h>
#include <math.h>

constexpr int   P      = 16;   // N_POINTS
constexpr int   DIN    = 48;   // P*3
constexpr int   DH     = 64;   // hidden dim
constexpr int   NITER  = 8;    // I
constexpr int   NLAYER = 2;    // L
constexpr float BIGV   = 1e9f;
constexpr float TAU    = 1e-4f;   // |cls| / |dval| borderline threshold
constexpr float VARMIN = 1e-3f;   // LN variance floor -> rsqrt amplification risk

// ---------------------------------------------------------------------------
// SLOW PATH (rare): elementwise ops in correctly-rounded f32 (bit-matching the
// references' shared per-op rounding), reductions in f64 (near-exact -> lands
// between the two references' reduction-order noise).
// ---------------------------------------------------------------------------
__device__ __noinline__
void slow_eval(float o0, float o1, float o2, float v0, float v1, float v2,
               float t1i, float t2i,
               const float* __restrict__ W_in,  const float* __restrict__ b_in,
               const float* __restrict__ ln_g,  const float* __restrict__ ln_b,
               const float* __restrict__ W_mid, const float* __restrict__ b_mid,
               const float* __restrict__ W_cls, const float* __restrict__ b_cls,
               const float* __restrict__ W_dist,const float* __restrict__ b_dist,
               float& cls_o, float& dval_o)
{
    const float dt  = __fsub_rn(t2i, t1i);
    const float io0 = __fadd_rn(o0, __fmul_rn(v0, t1i));
    const float io1 = __fadd_rn(o1, __fmul_rn(v1, t1i));
    const float io2 = __fadd_rn(o2, __fmul_rn(v2, t1i));
    const float iv0 = __fmul_rn(v0, dt);
    const float iv1 = __fmul_rn(v1, dt);
    const float iv2 = __fmul_rn(v2, dt);
    const float delta = 1.0f / 15.0f;        // f32(1/15): jnp.linspace step

    float x[DIN];
    #pragma unroll
    for (int p = 0; p < P; ++p) {
        const float tp = __fmul_rn((float)p, delta);   // f32(p * step)
        x[3*p+0] = __fdiv_rn(__fadd_rn(io0, __fmul_rn(iv0, tp)), 2.5f);
        x[3*p+1] = __fdiv_rn(__fadd_rn(io1, __fmul_rn(iv1, tp)), 2.5f);
        x[3*p+2] = __fdiv_rn(__fadd_rn(io2, __fmul_rn(iv2, tp)), 2.5f);
    }

    float a[DH];   // rolled-loop indexed -> scratch; fine on this rare path

    // input layer: exact-f64 dot of f32 values, then f32 bias add
    #pragma unroll 1
    for (int d = 0; d < DH; ++d) {
        double acc0 = 0.0, acc1 = 0.0;
        #pragma unroll
        for (int k = 0; k < DIN; k += 2) {
            acc0 = fma((double)x[k],   (double)W_in[k*DH + d],     acc0);
            acc1 = fma((double)x[k+1], (double)W_in[(k+1)*DH + d], acc1);
        }
        a[d] = __fadd_rn((float)(acc0 + acc1), b_in[d]);
    }

    #pragma unroll 1
    for (int l = 0; l < NLAYER; ++l) {
        #pragma unroll 1
        for (int d = 0; d < DH; ++d) a[d] = fmaxf(a[d], 0.0f);

        double s = 0.0;
        #pragma unroll 1
        for (int d = 0; d < DH; ++d) s += (double)a[d];
        const float mu = (float)(s * (1.0 / 64.0));

        double vs = 0.0;
        #pragma unroll 1
        for (int d = 0; d < DH; ++d) {
            const float c = __fsub_rn(a[d], mu);
            vs = fma((double)c, (double)c, vs);
        }
        const float var = (float)(vs * (1.0 / 64.0));
        const float ve  = __fadd_rn(var, 1e-5f);
        const float inv = (float)(1.0 / sqrt((double)ve));  // ~correctly-rounded f32 rsqrt

        float hn[DH];
        #pragma unroll 1
        for (int d = 0; d < DH; ++d) {
            float t = __fsub_rn(a[d], mu);
            t = __fmul_rn(t, inv);
            t = __fmul_rn(t, ln_g[l*DH + d]);
            hn[d] = __fadd_rn(t, ln_b[l*DH + d]);
        }

        #pragma unroll 1
        for (int d = 0; d < DH; ++d) {
            double acc0 = 0.0, acc1 = 0.0;
            #pragma unroll
            for (int k = 0; k < DH; k += 2) {
                acc0 = fma((double)hn[k],   (double)W_mid[(l*DH + k)*DH + d],   acc0);
                acc1 = fma((double)hn[k+1], (double)W_mid[(l*DH + k+1)*DH + d], acc1);
            }
            a[d] = __fadd_rn((float)(acc0 + acc1), b_mid[l*DH + d]);
        }
    }

    double c0 = 0.0, c1 = 0.0, d0 = 0.0, d1 = 0.0;
    #pragma unroll 1
    for (int d = 0; d < DH; d += 2) {
        const float h0 = fmaxf(a[d],   0.0f);
        const float h1 = fmaxf(a[d+1], 0.0f);
        c0 = fma((double)h0, (double)W_cls[d],    c0);
        c1 = fma((double)h1, (double)W_cls[d+1],  c1);
        d0 = fma((double)h0, (double)W_dist[d],   d0);
        d1 = fma((double)h1, (double)W_dist[d+1], d1);
    }
    const float cls = __fadd_rn((float)(c0 + c1), b_cls[0]);
    const float dv  = __fadd_rn((float)(d0 + d1), b_dist[0]);
    cls_o  = cls;
    dval_o = __fadd_rn(__fmul_rn(dv, dt), t1i);
}

// ---------------------------------------------------------------------------
// FAST PATH kernel: fully-unrolled f32 MLP per ray, f64 recheck on borderline
// candidates only.
// ---------------------------------------------------------------------------
__global__ __launch_bounds__(256)
void nbvh_fused(const float* __restrict__ orig,
                const float* __restrict__ vec,
                const float* __restrict__ t1,
                const float* __restrict__ t2,
                const int*   __restrict__ mask,
                const float* __restrict__ W_in,
                const float* __restrict__ b_in,
                const float* __restrict__ ln_g,
                const float* __restrict__ ln_b,
                const float* __restrict__ W_mid,
                const float* __restrict__ b_mid,
                const float* __restrict__ W_cls,
                const float* __restrict__ b_cls,
                const float* __restrict__ W_dist,
                const float* __restrict__ b_dist,
                float* __restrict__ out,
                int R)
{
    const int r = blockIdx.x * blockDim.x + threadIdx.x;
    if (r >= R) return;

    const float o0 = orig[3*r+0], o1 = orig[3*r+1], o2 = orig[3*r+2];
    const float v0 = vec[3*r+0],  v1 = vec[3*r+1],  v2 = vec[3*r+2];

    float dist = BIGV;

    #pragma unroll 1
    for (int i = 0; i < NITER; ++i) {
        const float t1i = t1[(size_t)i * R + r];
        const float t2i = t2[(size_t)i * R + r];
        const int   mi  = mask[(size_t)i * R + r];
        if (!mi) continue;                 // exact: update requires mask
        const float dt = t2i - t1i;

        float a[DH];
        float minvar = 1e30f;

        // ---- input layer
        {
            const float io0 = o0 + v0 * t1i;
            const float io1 = o1 + v1 * t1i;
            const float io2 = o2 + v2 * t1i;
            const float iv0 = v0 * dt, iv1 = v1 * dt, iv2 = v2 * dt;
            const float delta = 1.0f / 15.0f;

            float x[DIN];
            #pragma unroll
            for (int p = 0; p < P; ++p) {
                const float tp = (float)p * delta;
                x[3*p+0] = (io0 + iv0 * tp) / 2.5f;
                x[3*p+1] = (io1 + iv1 * tp) / 2.5f;
                x[3*p+2] = (io2 + iv2 * tp) / 2.5f;
            }

            #pragma unroll
            for (int d = 0; d < DH; ++d) a[d] = 0.0f;
            #pragma unroll
            for (int k = 0; k < DIN; ++k) {
                const float xk = x[k];
                #pragma unroll
                for (int d = 0; d < DH; ++d)
                    a[d] = fmaf(xk, W_in[k*DH + d], a[d]);
            }
            #pragma unroll
            for (int d = 0; d < DH; ++d) a[d] += b_in[d];
        }

        // ---- two mid layers: relu -> layernorm -> matmul
        #pragma unroll 1
        for (int l = 0; l < NLAYER; ++l) {
            #pragma unroll
            for (int d = 0; d < DH; ++d) a[d] = fmaxf(a[d], 0.0f);

            float mu = 0.0f;
            #pragma unroll
            for (int d = 0; d < DH; ++d) mu += a[d];
            mu *= (1.0f / 64.0f);

            float var = 0.0f;
            #pragma unroll
            for (int d = 0; d < DH; ++d) {
                const float c = a[d] - mu;
                var = fmaf(c, c, var);
            }
            var *= (1.0f / 64.0f);
            minvar = fminf(minvar, var);
            const float inv = 1.0f / sqrtf(var + 1e-5f);

            float hn[DH];
            #pragma unroll
            for (int d = 0; d < DH; ++d)
                hn[d] = (a[d] - mu) * inv * ln_g[l*DH + d] + ln_b[l*DH + d];

            #pragma unroll
            for (int d = 0; d < DH; ++d) a[d] = 0.0f;
            #pragma unroll
            for (int k = 0; k < DH; ++k) {
                const float hk = hn[k];
                #pragma unroll
                for (int d = 0; d < DH; ++d)
                    a[d] = fmaf(hk, W_mid[(l*DH + k)*DH + d], a[d]);
            }
            #pragma unroll
            for (int d = 0; d < DH; ++d) a[d] += b_mid[l*DH + d];
        }

        // ---- heads
        #pragma unroll
        for (int d = 0; d < DH; ++d) a[d] = fmaxf(a[d], 0.0f);

        float cls = 0.0f, dv = 0.0f;
        #pragma unroll
        for (int d = 0; d < DH; ++d) {
            cls = fmaf(a[d], W_cls[d],  cls);
            dv  = fmaf(a[d], W_dist[d], dv);
        }
        cls += b_cls[0];
        dv  += b_dist[0];

        float dval = dv * dt + t1i;

        // ---- borderline? recompute this candidate precisely
        const bool risky = (fabsf(cls) < TAU) | (fabsf(dval) < TAU) |
                           (minvar < VARMIN);
        if (risky) {
            slow_eval(o0, o1, o2, v0, v1, v2, t1i, t2i,
                      W_in, b_in, ln_g, ln_b, W_mid, b_mid,
                      W_cls, b_cls, W_dist, b_dist, cls, dval);
        }

        if (cls > 0.0f && dval < dist) dist = dval;
    }

    const float dfin = (dist == BIGV) ? 0.0f : dist;
    out[r]     = (dfin > 0.0f) ? 1.0f : 0.0f;   // output 0: dist > 0
    out[R + r] = dfin;                          // output 1: dist
}

extern "C" void kernel_launch(void* const* d_in, const int* in_sizes, int n_in,
                              void* d_out, int out_size, void* d_ws, size_t ws_size,
                              hipStream_t stream) {
    const float* orig   = (const float*)d_in[0];
    const float* vec    = (const float*)d_in[1];
    const float* t1     = (const float*)d_in[2];
    const float* t2     = (const float*)d_in[3];
    const int*   mask   = (const int*)  d_in[4];
    const float* W_in   = (const float*)d_in[5];
    const float* b_in   = (const float*)d_in[6];
    const float* ln_g   = (const float*)d_in[7];
    const float* ln_b   = (const float*)d_in[8];
    const float* W_mid  = (const float*)d_in[9];
    const float* b_mid  = (const float*)d_in[10];
    const float* W_cls  = (const float*)d_in[11];
    const float* b_cls  = (const float*)d_in[12];
    const float* W_dist = (const float*)d_in[13];
    const float* b_dist = (const float*)d_in[14];

    float* out = (float*)d_out;
    const int R = in_sizes[0] / 3;

    const int threads = 256;
    const int blocks  = (R + threads - 1) / threads;
    nbvh_fused<<<blocks, threads, 0, stream>>>(
        orig, vec, t1, t2, mask,
        W_in, b_in, ln_g, ln_b, W_mid, b_mid,
        W_cls, b_cls, W_dist, b_dist,
        out, R);
}

// Round 3
// 20708.241 us; speedup vs baseline: 1.5031x; 1.5031x over previous
//
#include <hip/hip_runtime.h>
#include <hip/hip_bf16.h>
#include <math.h>

constexpr int   P      = 16;   // N_POINTS
constexpr int   DIN    = 48;   // P*3
constexpr int   DH     = 64;   // hidden dim
constexpr int   NITER  = 8;    // I
constexpr int   NLAYER = 2;    // L
constexpr float BIGV   = 1e9f;
constexpr float TAU    = 1e-4f;   // |cls| / |dval| borderline threshold
constexpr float VARMIN = 1e-3f;   // LN variance floor
constexpr float INV_R  = 1.0f / 2.5f;

// ---------------------------------------------------------------------------
// SLOW PATH (rare): elementwise ops in correctly-rounded f32, reductions in
// f64. Re-adjudicates borderline candidates; absorbs fast-path rounding diffs.
// ---------------------------------------------------------------------------
__device__ __noinline__
void slow_eval(float o0, float o1, float o2, float v0, float v1, float v2,
               float t1i, float t2i,
               const float* __restrict__ W_in,  const float* __restrict__ b_in,
               const float* __restrict__ ln_g,  const float* __restrict__ ln_b,
               const float* __restrict__ W_mid, const float* __restrict__ b_mid,
               const float* __restrict__ W_cls, const float* __restrict__ b_cls,
               const float* __restrict__ W_dist,const float* __restrict__ b_dist,
               float& cls_o, float& dval_o)
{
    const float dt  = __fsub_rn(t2i, t1i);
    const float io0 = __fadd_rn(o0, __fmul_rn(v0, t1i));
    const float io1 = __fadd_rn(o1, __fmul_rn(v1, t1i));
    const float io2 = __fadd_rn(o2, __fmul_rn(v2, t1i));
    const float iv0 = __fmul_rn(v0, dt);
    const float iv1 = __fmul_rn(v1, dt);
    const float iv2 = __fmul_rn(v2, dt);
    const float delta = 1.0f / 15.0f;

    float x[DIN];
    #pragma unroll
    for (int p = 0; p < P; ++p) {
        const float tp = __fmul_rn((float)p, delta);
        x[3*p+0] = __fdiv_rn(__fadd_rn(io0, __fmul_rn(iv0, tp)), 2.5f);
        x[3*p+1] = __fdiv_rn(__fadd_rn(io1, __fmul_rn(iv1, tp)), 2.5f);
        x[3*p+2] = __fdiv_rn(__fadd_rn(io2, __fmul_rn(iv2, tp)), 2.5f);
    }

    float a[DH];

    #pragma unroll 1
    for (int d = 0; d < DH; ++d) {
        double acc0 = 0.0, acc1 = 0.0;
        #pragma unroll
        for (int k = 0; k < DIN; k += 2) {
            acc0 = fma((double)x[k],   (double)W_in[k*DH + d],     acc0);
            acc1 = fma((double)x[k+1], (double)W_in[(k+1)*DH + d], acc1);
        }
        a[d] = __fadd_rn((float)(acc0 + acc1), b_in[d]);
    }

    #pragma unroll 1
    for (int l = 0; l < NLAYER; ++l) {
        #pragma unroll 1
        for (int d = 0; d < DH; ++d) a[d] = fmaxf(a[d], 0.0f);

        double s = 0.0;
        #pragma unroll 1
        for (int d = 0; d < DH; ++d) s += (double)a[d];
        const float mu = (float)(s * (1.0 / 64.0));

        double vs = 0.0;
        #pragma unroll 1
        for (int d = 0; d < DH; ++d) {
            const float c = __fsub_rn(a[d], mu);
            vs = fma((double)c, (double)c, vs);
        }
        const float var = (float)(vs * (1.0 / 64.0));
        const float ve  = __fadd_rn(var, 1e-5f);
        const float inv = (float)(1.0 / sqrt((double)ve));

        float hn[DH];
        #pragma unroll 1
        for (int d = 0; d < DH; ++d) {
            float t = __fsub_rn(a[d], mu);
            t = __fmul_rn(t, inv);
            t = __fmul_rn(t, ln_g[l*DH + d]);
            hn[d] = __fadd_rn(t, ln_b[l*DH + d]);
        }

        #pragma unroll 1
        for (int d = 0; d < DH; ++d) {
            double acc0 = 0.0, acc1 = 0.0;
            #pragma unroll
            for (int k = 0; k < DH; k += 2) {
                acc0 = fma((double)hn[k],   (double)W_mid[(l*DH + k)*DH + d],   acc0);
                acc1 = fma((double)hn[k+1], (double)W_mid[(l*DH + k+1)*DH + d], acc1);
            }
            a[d] = __fadd_rn((float)(acc0 + acc1), b_mid[l*DH + d]);
        }
    }

    double c0 = 0.0, c1 = 0.0, d0 = 0.0, d1 = 0.0;
    #pragma unroll 1
    for (int d = 0; d < DH; d += 2) {
        const float h0 = fmaxf(a[d],   0.0f);
        const float h1 = fmaxf(a[d+1], 0.0f);
        c0 = fma((double)h0, (double)W_cls[d],    c0);
        c1 = fma((double)h1, (double)W_cls[d+1],  c1);
        d0 = fma((double)h0, (double)W_dist[d],   d0);
        d1 = fma((double)h1, (double)W_dist[d+1], d1);
    }
    const float cls = __fadd_rn((float)(c0 + c1), b_cls[0]);
    const float dv  = __fadd_rn((float)(d0 + d1), b_dist[0]);
    cls_o  = cls;
    dval_o = __fadd_rn(__fmul_rn(dv, dt), t1i);
}

// ---------------------------------------------------------------------------
// FAST PATH: rolled k-loops (I-cache resident). Per-lane activation column in
// LDS (act[k][lane], 2-way bank alias = free) solves the runtime-k register-
// indexing problem; accumulators a[64] stay in registers (static d indexing).
// Weight rows are wave-uniform -> scalar loads, each row feeds 64 FMAs.
// ---------------------------------------------------------------------------
__global__ __launch_bounds__(128)
void nbvh_fused(const float* __restrict__ orig,
                const float* __restrict__ vec,
                const float* __restrict__ t1,
                const float* __restrict__ t2,
                const int*   __restrict__ mask,
                const float* __restrict__ W_in,
                const float* __restrict__ b_in,
                const float* __restrict__ ln_g,
                const float* __restrict__ ln_b,
                const float* __restrict__ W_mid,
                const float* __restrict__ b_mid,
                const float* __restrict__ W_cls,
                const float* __restrict__ b_cls,
                const float* __restrict__ W_dist,
                const float* __restrict__ b_dist,
                float* __restrict__ out,
                int R)
{
    __shared__ float act[2][DH][64];   // [wave][k][lane] = 32 KiB

    const int tid  = threadIdx.x;
    const int lane = tid & 63;
    const int wv   = tid >> 6;
    const int r    = blockIdx.x * 128 + tid;
    if (r >= R) return;                // no barriers below -> early-exit safe

    float* myact = &act[wv][0][lane];  // element k lives at myact[k*64]

    const float o0 = orig[3*r+0], o1 = orig[3*r+1], o2 = orig[3*r+2];
    const float v0 = vec[3*r+0],  v1 = vec[3*r+1],  v2 = vec[3*r+2];

    float dist = BIGV;

    #pragma unroll 1
    for (int i = 0; i < NITER; ++i) {
        const float t1i = t1[(size_t)i * R + r];
        const float t2i = t2[(size_t)i * R + r];
        const int   mi  = mask[(size_t)i * R + r];
        if (!mi) continue;             // exact: update requires mask
        const float dt = t2i - t1i;

        const float io0 = fmaf(v0, t1i, o0);
        const float io1 = fmaf(v1, t1i, o1);
        const float io2 = fmaf(v2, t1i, o2);
        const float iv0 = v0 * dt, iv1 = v1 * dt, iv2 = v2 * dt;

        // ---- build x directly into LDS (static k indices)
        #pragma unroll
        for (int p = 0; p < P; ++p) {
            const float tp = (float)p * (1.0f / 15.0f);
            myact[(3*p+0)*64] = fmaf(iv0, tp, io0) * INV_R;
            myact[(3*p+1)*64] = fmaf(iv1, tp, io1) * INV_R;
            myact[(3*p+2)*64] = fmaf(iv2, tp, io2) * INV_R;
        }

        float a[DH];
        #pragma unroll
        for (int d = 0; d < DH; ++d) a[d] = 0.0f;

        // ---- input layer: rolled k, uniform weight-row loads
        #pragma unroll 1
        for (int k = 0; k < DIN; ++k) {
            const float xk = myact[k*64];
            const float4* wr = (const float4*)(W_in + k*DH);
            #pragma unroll
            for (int j = 0; j < 16; ++j) {
                const float4 w4 = wr[j];
                a[4*j+0] = fmaf(xk, w4.x, a[4*j+0]);
                a[4*j+1] = fmaf(xk, w4.y, a[4*j+1]);
                a[4*j+2] = fmaf(xk, w4.z, a[4*j+2]);
                a[4*j+3] = fmaf(xk, w4.w, a[4*j+3]);
            }
        }
        #pragma unroll
        for (int d = 0; d < DH; ++d) a[d] += b_in[d];

        float minvar = 1e30f;

        // ---- mid layers: relu -> LN -> (hn via LDS) -> rolled-k matmul
        #pragma unroll 1
        for (int l = 0; l < NLAYER; ++l) {
            #pragma unroll
            for (int d = 0; d < DH; ++d) a[d] = fmaxf(a[d], 0.0f);

            float mu = 0.0f;
            #pragma unroll
            for (int d = 0; d < DH; ++d) mu += a[d];
            mu *= (1.0f / 64.0f);

            float var = 0.0f;
            #pragma unroll
            for (int d = 0; d < DH; ++d) {
                const float c = a[d] - mu;
                var = fmaf(c, c, var);
            }
            var *= (1.0f / 64.0f);
            minvar = fminf(minvar, var);
            const float inv = 1.0f / sqrtf(var + 1e-5f);

            const float* g  = ln_g + l*DH;
            const float* bb = ln_b + l*DH;
            #pragma unroll
            for (int d = 0; d < DH; ++d)
                myact[d*64] = fmaf((a[d] - mu) * inv, g[d], bb[d]);

            #pragma unroll
            for (int d = 0; d < DH; ++d) a[d] = 0.0f;

            const float* Wl = W_mid + l*DH*DH;
            #pragma unroll 1
            for (int k = 0; k < DH; ++k) {
                const float hk = myact[k*64];
                const float4* wr = (const float4*)(Wl + k*DH);
                #pragma unroll
                for (int j = 0; j < 16; ++j) {
                    const float4 w4 = wr[j];
                    a[4*j+0] = fmaf(hk, w4.x, a[4*j+0]);
                    a[4*j+1] = fmaf(hk, w4.y, a[4*j+1]);
                    a[4*j+2] = fmaf(hk, w4.z, a[4*j+2]);
                    a[4*j+3] = fmaf(hk, w4.w, a[4*j+3]);
                }
            }
            const float* bm = b_mid + l*DH;
            #pragma unroll
            for (int d = 0; d < DH; ++d) a[d] += bm[d];
        }

        // ---- heads (unrolled, small)
        #pragma unroll
        for (int d = 0; d < DH; ++d) a[d] = fmaxf(a[d], 0.0f);

        float cls = 0.0f, dv = 0.0f;
        #pragma unroll
        for (int d = 0; d < DH; ++d) {
            cls = fmaf(a[d], W_cls[d],  cls);
            dv  = fmaf(a[d], W_dist[d], dv);
        }
        cls += b_cls[0];
        dv  += b_dist[0];

        float dval = fmaf(dv, dt, t1i);

        const bool risky = (fabsf(cls) < TAU) | (fabsf(dval) < TAU) |
                           (minvar < VARMIN);
        if (risky) {
            slow_eval(o0, o1, o2, v0, v1, v2, t1i, t2i,
                      W_in, b_in, ln_g, ln_b, W_mid, b_mid,
                      W_cls, b_cls, W_dist, b_dist, cls, dval);
        }

        if (cls > 0.0f && dval < dist) dist = dval;
    }

    const float dfin = (dist == BIGV) ? 0.0f : dist;
    out[r]     = (dfin > 0.0f) ? 1.0f : 0.0f;
    out[R + r] = dfin;
}

extern "C" void kernel_launch(void* const* d_in, const int* in_sizes, int n_in,
                              void* d_out, int out_size, void* d_ws, size_t ws_size,
                              hipStream_t stream) {
    const float* orig   = (const float*)d_in[0];
    const float* vec    = (const float*)d_in[1];
    const float* t1     = (const float*)d_in[2];
    const float* t2     = (const float*)d_in[3];
    const int*   mask   = (const int*)  d_in[4];
    const float* W_in   = (const float*)d_in[5];
    const float* b_in   = (const float*)d_in[6];
    const float* ln_g   = (const float*)d_in[7];
    const float* ln_b   = (const float*)d_in[8];
    const float* W_mid  = (const float*)d_in[9];
    const float* b_mid  = (const float*)d_in[10];
    const float* W_cls  = (const float*)d_in[11];
    const float* b_cls  = (const float*)d_in[12];
    const float* W_dist = (const float*)d_in[13];
    const float* b_dist = (const float*)d_in[14];

    float* out = (float*)d_out;
    const int R = in_sizes[0] / 3;

    const int threads = 128;
    const int blocks  = (R + threads - 1) / threads;
    nbvh_fused<<<blocks, threads, 0, stream>>>(
        orig, vec, t1, t2, mask,
        W_in, b_in, ln_g, ln_b, W_mid, b_mid,
        W_cls, b_cls, W_dist, b_dist,
        out, R);
}

// Round 4
// 11017.025 us; speedup vs baseline: 2.8254x; 1.8797x over previous
//
#include <hip/hip_runtime.h>
#include <math.h>

constexpr int   P      = 16;   // N_POINTS
constexpr int   DIN    = 48;   // P*3
constexpr int   DH     = 64;   // hidden dim
constexpr int   NITER  = 8;    // I
constexpr int   NLAYER = 2;    // L
constexpr float BIGV   = 1e9f;
constexpr float INV_R  = 1.0f / 2.5f;

typedef float f32x4 __attribute__((ext_vector_type(4)));
typedef const __attribute__((address_space(1))) f32x4 gf4_t;

// Launder a wave-uniform address so the compiler cannot scalarize the load:
// keeps weight loads on the VMEM/vmcnt path (global_load_dwordx4, L1-broadcast)
// instead of s_load on lgkmcnt, which would serialize against ds_read waits.
__device__ __forceinline__ gf4_t* vmem(const float* p) {
    unsigned long long a = (unsigned long long)p;
    asm volatile("" : "+v"(a));
    return (gf4_t*)a;
}

// ---------------------------------------------------------------------------
// SLOW PATH (rare): elementwise ops in correctly-rounded f32, reductions in
// f64. Byte-identical to the round-2/3 version that passed validation.
// ---------------------------------------------------------------------------
__device__ __noinline__
void slow_eval(float o0, float o1, float o2, float v0, float v1, float v2,
               float t1i, float t2i,
               const float* __restrict__ W_in,  const float* __restrict__ b_in,
               const float* __restrict__ ln_g,  const float* __restrict__ ln_b,
               const float* __restrict__ W_mid, const float* __restrict__ b_mid,
               const float* __restrict__ W_cls, const float* __restrict__ b_cls,
               const float* __restrict__ W_dist,const float* __restrict__ b_dist,
               float& cls_o, float& dval_o)
{
    const float dt  = __fsub_rn(t2i, t1i);
    const float io0 = __fadd_rn(o0, __fmul_rn(v0, t1i));
    const float io1 = __fadd_rn(o1, __fmul_rn(v1, t1i));
    const float io2 = __fadd_rn(o2, __fmul_rn(v2, t1i));
    const float iv0 = __fmul_rn(v0, dt);
    const float iv1 = __fmul_rn(v1, dt);
    const float iv2 = __fmul_rn(v2, dt);
    const float delta = 1.0f / 15.0f;

    float x[DIN];
    #pragma unroll
    for (int p = 0; p < P; ++p) {
        const float tp = __fmul_rn((float)p, delta);
        x[3*p+0] = __fdiv_rn(__fadd_rn(io0, __fmul_rn(iv0, tp)), 2.5f);
        x[3*p+1] = __fdiv_rn(__fadd_rn(io1, __fmul_rn(iv1, tp)), 2.5f);
        x[3*p+2] = __fdiv_rn(__fadd_rn(io2, __fmul_rn(iv2, tp)), 2.5f);
    }

    float a[DH];

    #pragma unroll 1
    for (int d = 0; d < DH; ++d) {
        double acc0 = 0.0, acc1 = 0.0;
        #pragma unroll
        for (int k = 0; k < DIN; k += 2) {
            acc0 = fma((double)x[k],   (double)W_in[k*DH + d],     acc0);
            acc1 = fma((double)x[k+1], (double)W_in[(k+1)*DH + d], acc1);
        }
        a[d] = __fadd_rn((float)(acc0 + acc1), b_in[d]);
    }

    #pragma unroll 1
    for (int l = 0; l < NLAYER; ++l) {
        #pragma unroll 1
        for (int d = 0; d < DH; ++d) a[d] = fmaxf(a[d], 0.0f);

        double s = 0.0;
        #pragma unroll 1
        for (int d = 0; d < DH; ++d) s += (double)a[d];
        const float mu = (float)(s * (1.0 / 64.0));

        double vs = 0.0;
        #pragma unroll 1
        for (int d = 0; d < DH; ++d) {
            const float c = __fsub_rn(a[d], mu);
            vs = fma((double)c, (double)c, vs);
        }
        const float var = (float)(vs * (1.0 / 64.0));
        const float ve  = __fadd_rn(var, 1e-5f);
        const float inv = (float)(1.0 / sqrt((double)ve));

        float hn[DH];
        #pragma unroll 1
        for (int d = 0; d < DH; ++d) {
            float t = __fsub_rn(a[d], mu);
            t = __fmul_rn(t, inv);
            t = __fmul_rn(t, ln_g[l*DH + d]);
            hn[d] = __fadd_rn(t, ln_b[l*DH + d]);
        }

        #pragma unroll 1
        for (int d = 0; d < DH; ++d) {
            double acc0 = 0.0, acc1 = 0.0;
            #pragma unroll
            for (int k = 0; k < DH; k += 2) {
                acc0 = fma((double)hn[k],   (double)W_mid[(l*DH + k)*DH + d],   acc0);
                acc1 = fma((double)hn[k+1], (double)W_mid[(l*DH + k+1)*DH + d], acc1);
            }
            a[d] = __fadd_rn((float)(acc0 + acc1), b_mid[l*DH + d]);
        }
    }

    double c0 = 0.0, c1 = 0.0, d0 = 0.0, d1 = 0.0;
    #pragma unroll 1
    for (int d = 0; d < DH; d += 2) {
        const float h0 = fmaxf(a[d],   0.0f);
        const float h1 = fmaxf(a[d+1], 0.0f);
        c0 = fma((double)h0, (double)W_cls[d],    c0);
        c1 = fma((double)h1, (double)W_cls[d+1],  c1);
        d0 = fma((double)h0, (double)W_dist[d],   d0);
        d1 = fma((double)h1, (double)W_dist[d+1], d1);
    }
    const float cls = __fadd_rn((float)(c0 + c1), b_cls[0]);
    const float dv  = __fadd_rn((float)(d0 + d1), b_dist[0]);
    cls_o  = cls;
    dval_o = __fadd_rn(__fmul_rn(dv, dt), t1i);
}

// ---------------------------------------------------------------------------
// FAST PATH: input layer fully inline (no LDS); mid-layer activations transit
// through a per-lane LDS column (2-way bank alias = free); weight rows go
// through laundered VMEM loads (vmcnt) so they pipeline independently of the
// ds_read (lgkmcnt) waits. Accumulation order matches the validated kernel.
// ---------------------------------------------------------------------------
__global__ __launch_bounds__(128, 2)
void nbvh_fused(const float* __restrict__ orig,
                const float* __restrict__ vec,
                const float* __restrict__ t1,
                const float* __restrict__ t2,
                const int*   __restrict__ mask,
                const float* __restrict__ W_in,
                const float* __restrict__ b_in,
                const float* __restrict__ ln_g,
                const float* __restrict__ ln_b,
                const float* __restrict__ W_mid,
                const float* __restrict__ b_mid,
                const float* __restrict__ W_cls,
                const float* __restrict__ b_cls,
                const float* __restrict__ W_dist,
                const float* __restrict__ b_dist,
                float* __restrict__ out,
                int R)
{
    __shared__ float act[2][DH][64];   // [wave][k][lane] = 32 KiB

    const int tid  = threadIdx.x;
    const int lane = tid & 63;
    const int wv   = tid >> 6;
    const int r    = blockIdx.x * 128 + tid;
    if (r >= R) return;                // no barriers below -> early-exit safe

    float* myact = &act[wv][0][lane];  // element k lives at myact[k*64]

    const float o0 = orig[3*r+0], o1 = orig[3*r+1], o2 = orig[3*r+2];
    const float v0 = vec[3*r+0],  v1 = vec[3*r+1],  v2 = vec[3*r+2];

    float dist = BIGV;

    #pragma unroll 1
    for (int i = 0; i < NITER; ++i) {
        const float t1i = t1[(size_t)i * R + r];
        const float t2i = t2[(size_t)i * R + r];
        const int   mi  = mask[(size_t)i * R + r];
        if (!mi) continue;             // exact: update requires mask
        const float dt = t2i - t1i;

        const float io0 = fmaf(v0, t1i, o0);
        const float io1 = fmaf(v1, t1i, o1);
        const float io2 = fmaf(v2, t1i, o2);
        const float iv0 = v0 * dt, iv1 = v1 * dt, iv2 = v2 * dt;

        float a[DH];
        #pragma unroll
        for (int d = 0; d < DH; ++d) a[d] = 0.0f;

        // ---- input layer: x computed inline, 3 weight rows per p-step.
        // k-order inside fmaf nest is 3p, 3p+1, 3p+2 (innermost first) ->
        // identical accumulation order to the validated kernel.
        #pragma unroll 1
        for (int p = 0; p < P; ++p) {
            const float tp = (float)p * (1.0f / 15.0f);
            const float x0 = fmaf(iv0, tp, io0) * INV_R;
            const float x1 = fmaf(iv1, tp, io1) * INV_R;
            const float x2 = fmaf(iv2, tp, io2) * INV_R;
            gf4_t* w0 = vmem(W_in + (3*p+0)*DH);
            gf4_t* w1 = vmem(W_in + (3*p+1)*DH);
            gf4_t* w2 = vmem(W_in + (3*p+2)*DH);
            #pragma unroll
            for (int j = 0; j < 16; ++j) {
                const f32x4 u = w0[j], v4 = w1[j], w4 = w2[j];
                a[4*j+0] = fmaf(x2, w4.x, fmaf(x1, v4.x, fmaf(x0, u.x, a[4*j+0])));
                a[4*j+1] = fmaf(x2, w4.y, fmaf(x1, v4.y, fmaf(x0, u.y, a[4*j+1])));
                a[4*j+2] = fmaf(x2, w4.z, fmaf(x1, v4.z, fmaf(x0, u.z, a[4*j+2])));
                a[4*j+3] = fmaf(x2, w4.w, fmaf(x1, v4.w, fmaf(x0, u.w, a[4*j+3])));
            }
        }
        #pragma unroll
        for (int d = 0; d < DH; ++d) a[d] += b_in[d];

        float invprod = 1.0f;          // inv1*inv2: noise-amplification factor

        // ---- mid layers: relu -> LN (regs) -> LDS column -> rolled-k matmul
        #pragma unroll 1
        for (int l = 0; l < NLAYER; ++l) {
            #pragma unroll
            for (int d = 0; d < DH; ++d) a[d] = fmaxf(a[d], 0.0f);

            float mu = 0.0f;
            #pragma unroll
            for (int d = 0; d < DH; ++d) mu += a[d];
            mu *= (1.0f / 64.0f);

            float var = 0.0f;
            #pragma unroll
            for (int d = 0; d < DH; ++d) {
                const float c = a[d] - mu;
                var = fmaf(c, c, var);
            }
            var *= (1.0f / 64.0f);
            const float inv = 1.0f / sqrtf(var + 1e-5f);
            invprod *= inv;

            const float* g  = ln_g + l*DH;
            const float* bb = ln_b + l*DH;
            #pragma unroll
            for (int d = 0; d < DH; ++d)
                myact[d*64] = fmaf((a[d] - mu) * inv, g[d], bb[d]);

            #pragma unroll
            for (int d = 0; d < DH; ++d) a[d] = 0.0f;

            const float* Wl = W_mid + l*DH*DH;
            #pragma unroll 2
            for (int k = 0; k < DH; ++k) {
                const float hk = myact[k*64];
                gf4_t* wr = vmem(Wl + k*DH);
                #pragma unroll
                for (int j = 0; j < 16; ++j) {
                    const f32x4 w4 = wr[j];
                    a[4*j+0] = fmaf(hk, w4.x, a[4*j+0]);
                    a[4*j+1] = fmaf(hk, w4.y, a[4*j+1]);
                    a[4*j+2] = fmaf(hk, w4.z, a[4*j+2]);
                    a[4*j+3] = fmaf(hk, w4.w, a[4*j+3]);
                }
            }
            const float* bm = b_mid + l*DH;
            #pragma unroll
            for (int d = 0; d < DH; ++d) a[d] += bm[d];
        }

        // ---- heads (4 chains each to shorten fma dependency chains)
        #pragma unroll
        for (int d = 0; d < DH; ++d) a[d] = fmaxf(a[d], 0.0f);

        float c0 = 0.f, c1 = 0.f, c2 = 0.f, c3 = 0.f;
        float e0 = 0.f, e1 = 0.f, e2 = 0.f, e3 = 0.f;
        #pragma unroll
        for (int j = 0; j < 16; ++j) {
            c0 = fmaf(a[4*j+0], W_cls[4*j+0],  c0);
            c1 = fmaf(a[4*j+1], W_cls[4*j+1],  c1);
            c2 = fmaf(a[4*j+2], W_cls[4*j+2],  c2);
            c3 = fmaf(a[4*j+3], W_cls[4*j+3],  c3);
            e0 = fmaf(a[4*j+0], W_dist[4*j+0], e0);
            e1 = fmaf(a[4*j+1], W_dist[4*j+1], e1);
            e2 = fmaf(a[4*j+2], W_dist[4*j+2], e2);
            e3 = fmaf(a[4*j+3], W_dist[4*j+3], e3);
        }
        float cls = ((c0 + c1) + (c2 + c3)) + b_cls[0];
        float dv  = ((e0 + e1) + (e2 + e3)) + b_dist[0];

        float dval = fmaf(dv, dt, t1i);

        // ---- amplification-aware borderline detection
        float thr = 2e-6f * invprod;
        thr = fminf(fmaxf(thr, 3e-5f), 2e-2f);
        const bool risky = (fabsf(cls) < thr) || (fabsf(dval) < thr);
        if (risky) {
            slow_eval(o0, o1, o2, v0, v1, v2, t1i, t2i,
                      W_in, b_in, ln_g, ln_b, W_mid, b_mid,
                      W_cls, b_cls, W_dist, b_dist, cls, dval);
        }

        if (cls > 0.0f && dval < dist) dist = dval;
    }

    const float dfin = (dist == BIGV) ? 0.0f : dist;
    out[r]     = (dfin > 0.0f) ? 1.0f : 0.0f;
    out[R + r] = dfin;
}

extern "C" void kernel_launch(void* const* d_in, const int* in_sizes, int n_in,
                              void* d_out, int out_size, void* d_ws, size_t ws_size,
                              hipStream_t stream) {
    const float* orig   = (const float*)d_in[0];
    const float* vec    = (const float*)d_in[1];
    const float* t1     = (const float*)d_in[2];
    const float* t2     = (const float*)d_in[3];
    const int*   mask   = (const int*)  d_in[4];
    const float* W_in   = (const float*)d_in[5];
    const float* b_in   = (const float*)d_in[6];
    const float* ln_g   = (const float*)d_in[7];
    const float* ln_b   = (const float*)d_in[8];
    const float* W_mid  = (const float*)d_in[9];
    const float* b_mid  = (const float*)d_in[10];
    const float* W_cls  = (const float*)d_in[11];
    const float* b_cls  = (const float*)d_in[12];
    const float* W_dist = (const float*)d_in[13];
    const float* b_dist = (const float*)d_in[14];

    float* out = (float*)d_out;
    const int R = in_sizes[0] / 3;

    const int threads = 128;
    const int blocks  = (R + threads - 1) / threads;
    nbvh_fused<<<blocks, threads, 0, stream>>>(
        orig, vec, t1, t2, mask,
        W_in, b_in, ln_g, ln_b, W_mid, b_mid,
        W_cls, b_cls, W_dist, b_dist,
        out, R);
}

// Round 5
// 6627.384 us; speedup vs baseline: 4.6968x; 1.6623x over previous
//
#include <hip/hip_runtime.h>
#include <math.h>

constexpr int   P      = 16;   // N_POINTS
constexpr int   DIN    = 48;   // P*3
constexpr int   DH     = 64;   // hidden dim
constexpr int   NITER  = 8;    // I
constexpr int   NLAYER = 2;    // L
constexpr float BIGV   = 1e9f;
constexpr float INV_R  = 1.0f / 2.5f;

typedef float f32x4 __attribute__((ext_vector_type(4)));

// ---------------------------------------------------------------------------
// SLOW PATH (rare): elementwise ops in correctly-rounded f32, reductions in
// f64. Byte-identical to the round-2/3/4 version that passed validation.
// ---------------------------------------------------------------------------
__device__ __noinline__
void slow_eval(float o0, float o1, float o2, float v0, float v1, float v2,
               float t1i, float t2i,
               const float* __restrict__ W_in,  const float* __restrict__ b_in,
               const float* __restrict__ ln_g,  const float* __restrict__ ln_b,
               const float* __restrict__ W_mid, const float* __restrict__ b_mid,
               const float* __restrict__ W_cls, const float* __restrict__ b_cls,
               const float* __restrict__ W_dist,const float* __restrict__ b_dist,
               float& cls_o, float& dval_o)
{
    const float dt  = __fsub_rn(t2i, t1i);
    const float io0 = __fadd_rn(o0, __fmul_rn(v0, t1i));
    const float io1 = __fadd_rn(o1, __fmul_rn(v1, t1i));
    const float io2 = __fadd_rn(o2, __fmul_rn(v2, t1i));
    const float iv0 = __fmul_rn(v0, dt);
    const float iv1 = __fmul_rn(v1, dt);
    const float iv2 = __fmul_rn(v2, dt);
    const float delta = 1.0f / 15.0f;

    float x[DIN];
    #pragma unroll
    for (int p = 0; p < P; ++p) {
        const float tp = __fmul_rn((float)p, delta);
        x[3*p+0] = __fdiv_rn(__fadd_rn(io0, __fmul_rn(iv0, tp)), 2.5f);
        x[3*p+1] = __fdiv_rn(__fadd_rn(io1, __fmul_rn(iv1, tp)), 2.5f);
        x[3*p+2] = __fdiv_rn(__fadd_rn(io2, __fmul_rn(iv2, tp)), 2.5f);
    }

    float a[DH];

    #pragma unroll 1
    for (int d = 0; d < DH; ++d) {
        double acc0 = 0.0, acc1 = 0.0;
        #pragma unroll
        for (int k = 0; k < DIN; k += 2) {
            acc0 = fma((double)x[k],   (double)W_in[k*DH + d],     acc0);
            acc1 = fma((double)x[k+1], (double)W_in[(k+1)*DH + d], acc1);
        }
        a[d] = __fadd_rn((float)(acc0 + acc1), b_in[d]);
    }

    #pragma unroll 1
    for (int l = 0; l < NLAYER; ++l) {
        #pragma unroll 1
        for (int d = 0; d < DH; ++d) a[d] = fmaxf(a[d], 0.0f);

        double s = 0.0;
        #pragma unroll 1
        for (int d = 0; d < DH; ++d) s += (double)a[d];
        const float mu = (float)(s * (1.0 / 64.0));

        double vs = 0.0;
        #pragma unroll 1
        for (int d = 0; d < DH; ++d) {
            const float c = __fsub_rn(a[d], mu);
            vs = fma((double)c, (double)c, vs);
        }
        const float var = (float)(vs * (1.0 / 64.0));
        const float ve  = __fadd_rn(var, 1e-5f);
        const float inv = (float)(1.0 / sqrt((double)ve));

        float hn[DH];
        #pragma unroll 1
        for (int d = 0; d < DH; ++d) {
            float t = __fsub_rn(a[d], mu);
            t = __fmul_rn(t, inv);
            t = __fmul_rn(t, ln_g[l*DH + d]);
            hn[d] = __fadd_rn(t, ln_b[l*DH + d]);
        }

        #pragma unroll 1
        for (int d = 0; d < DH; ++d) {
            double acc0 = 0.0, acc1 = 0.0;
            #pragma unroll
            for (int k = 0; k < DH; k += 2) {
                acc0 = fma((double)hn[k],   (double)W_mid[(l*DH + k)*DH + d],   acc0);
                acc1 = fma((double)hn[k+1], (double)W_mid[(l*DH + k+1)*DH + d], acc1);
            }
            a[d] = __fadd_rn((float)(acc0 + acc1), b_mid[l*DH + d]);
        }
    }

    double c0 = 0.0, c1 = 0.0, d0 = 0.0, d1 = 0.0;
    #pragma unroll 1
    for (int d = 0; d < DH; d += 2) {
        const float h0 = fmaxf(a[d],   0.0f);
        const float h1 = fmaxf(a[d+1], 0.0f);
        c0 = fma((double)h0, (double)W_cls[d],    c0);
        c1 = fma((double)h1, (double)W_cls[d+1],  c1);
        d0 = fma((double)h0, (double)W_dist[d],   d0);
        d1 = fma((double)h1, (double)W_dist[d+1], d1);
    }
    const float cls = __fadd_rn((float)(c0 + c1), b_cls[0]);
    const float dv  = __fadd_rn((float)(d0 + d1), b_dist[0]);
    cls_o  = cls;
    dval_o = __fadd_rn(__fmul_rn(dv, dt), t1i);
}

// ---------------------------------------------------------------------------
// FAST PATH: W_in + W_mid staged in LDS once per block (shared, uniform
// broadcast ds_read_b128 -> no L2 latency in the inner loop, single lgkm
// counter domain). Activations transit a 32-float per-lane LDS column
// (k-halved matmul; upper half parks in 32 VGPRs) -> 76 KB LDS/block,
// 2 blocks/CU. FP values and accumulation order identical to round 4.
// ---------------------------------------------------------------------------
__global__ __launch_bounds__(256, 2)
void nbvh_fused(const float* __restrict__ orig,
                const float* __restrict__ vec,
                const float* __restrict__ t1,
                const float* __restrict__ t2,
                const int*   __restrict__ mask,
                const float* __restrict__ W_in,
                const float* __restrict__ b_in,
                const float* __restrict__ ln_g,
                const float* __restrict__ ln_b,
                const float* __restrict__ W_mid,
                const float* __restrict__ b_mid,
                const float* __restrict__ W_cls,
                const float* __restrict__ b_cls,
                const float* __restrict__ W_dist,
                const float* __restrict__ b_dist,
                float* __restrict__ out,
                int R)
{
    __shared__ __align__(16) float wlds[DIN*DH + NLAYER*DH*DH]; // 44 KiB
    __shared__ __align__(16) float act[4][32][64];              // 32 KiB

    const int tid  = threadIdx.x;
    const int lane = tid & 63;
    const int wv   = tid >> 6;

    // ---- stage weights into LDS (whole block cooperates), one barrier
    {
        f32x4*       dst = (f32x4*)wlds;
        const f32x4* s1  = (const f32x4*)W_in;    // 768 float4
        const f32x4* s2  = (const f32x4*)W_mid;   // 2048 float4
        #pragma unroll 1
        for (int idx = tid; idx < DIN*DH/4; idx += 256)        dst[idx] = s1[idx];
        #pragma unroll 1
        for (int idx = tid; idx < NLAYER*DH*DH/4; idx += 256)  dst[DIN*DH/4 + idx] = s2[idx];
    }
    __syncthreads();   // only barrier in the kernel

    const float* win_l  = wlds;             // [48][64]
    const float* wmid_l = wlds + DIN*DH;    // [2][64][64]

    const int r = blockIdx.x * 256 + tid;
    if (r >= R) return;

    float* myact = &act[wv][0][lane];       // element k lives at myact[k*64]

    const float o0 = orig[3*r+0], o1 = orig[3*r+1], o2 = orig[3*r+2];
    const float v0 = vec[3*r+0],  v1 = vec[3*r+1],  v2 = vec[3*r+2];

    float dist = BIGV;

    #pragma unroll 1
    for (int i = 0; i < NITER; ++i) {
        const float t1i = t1[(size_t)i * R + r];
        const float t2i = t2[(size_t)i * R + r];
        const int   mi  = mask[(size_t)i * R + r];
        if (!mi) continue;             // exact: update requires mask
        const float dt = t2i - t1i;

        const float io0 = fmaf(v0, t1i, o0);
        const float io1 = fmaf(v1, t1i, o1);
        const float io2 = fmaf(v2, t1i, o2);
        const float iv0 = v0 * dt, iv1 = v1 * dt, iv2 = v2 * dt;

        float a[DH];
        #pragma unroll
        for (int d = 0; d < DH; ++d) a[d] = 0.0f;

        // ---- input layer: x inline, weight rows from LDS (uniform b128).
        // Same fmaf nest/order as the validated round-4 kernel.
        #pragma unroll 1
        for (int p = 0; p < P; ++p) {
            const float tp = (float)p * (1.0f / 15.0f);
            const float x0 = fmaf(iv0, tp, io0) * INV_R;
            const float x1 = fmaf(iv1, tp, io1) * INV_R;
            const float x2 = fmaf(iv2, tp, io2) * INV_R;
            const f32x4* w0 = (const f32x4*)(win_l + (3*p+0)*DH);
            const f32x4* w1 = (const f32x4*)(win_l + (3*p+1)*DH);
            const f32x4* w2 = (const f32x4*)(win_l + (3*p+2)*DH);
            #pragma unroll
            for (int j = 0; j < 16; ++j) {
                const f32x4 u = w0[j], v4 = w1[j], w4 = w2[j];
                a[4*j+0] = fmaf(x2, w4.x, fmaf(x1, v4.x, fmaf(x0, u.x, a[4*j+0])));
                a[4*j+1] = fmaf(x2, w4.y, fmaf(x1, v4.y, fmaf(x0, u.y, a[4*j+1])));
                a[4*j+2] = fmaf(x2, w4.z, fmaf(x1, v4.z, fmaf(x0, u.z, a[4*j+2])));
                a[4*j+3] = fmaf(x2, w4.w, fmaf(x1, v4.w, fmaf(x0, u.w, a[4*j+3])));
            }
        }
        #pragma unroll
        for (int d = 0; d < DH; ++d) a[d] += b_in[d];

        float invprod = 1.0f;          // inv1*inv2: noise-amplification factor

        // ---- mid layers: relu -> LN -> k-halved LDS matmul
        #pragma unroll 1
        for (int l = 0; l < NLAYER; ++l) {
            #pragma unroll
            for (int d = 0; d < DH; ++d) a[d] = fmaxf(a[d], 0.0f);

            float mu = 0.0f;
            #pragma unroll
            for (int d = 0; d < DH; ++d) mu += a[d];
            mu *= (1.0f / 64.0f);

            float var = 0.0f;
            #pragma unroll
            for (int d = 0; d < DH; ++d) {
                const float c = a[d] - mu;
                var = fmaf(c, c, var);
            }
            var *= (1.0f / 64.0f);
            const float inv = 1.0f / sqrtf(var + 1e-5f);
            invprod *= inv;

            const float* g  = ln_g + l*DH;
            const float* bb = ln_b + l*DH;

            // lower half of hn -> LDS; upper half -> 32 temp regs
            #pragma unroll
            for (int d = 0; d < 32; ++d)
                myact[d*64] = fmaf((a[d] - mu) * inv, g[d], bb[d]);
            float hh[32];
            #pragma unroll
            for (int j = 0; j < 32; ++j)
                hh[j] = fmaf((a[32+j] - mu) * inv, g[32+j], bb[32+j]);

            #pragma unroll
            for (int d = 0; d < DH; ++d) a[d] = 0.0f;

            const float* Wl = wmid_l + l*DH*DH;

            // k = 0..31 from LDS
            #pragma unroll 4
            for (int k = 0; k < 32; ++k) {
                const float hk = myact[k*64];
                const f32x4* wr = (const f32x4*)(Wl + k*DH);
                #pragma unroll
                for (int j = 0; j < 16; ++j) {
                    const f32x4 w4 = wr[j];
                    a[4*j+0] = fmaf(hk, w4.x, a[4*j+0]);
                    a[4*j+1] = fmaf(hk, w4.y, a[4*j+1]);
                    a[4*j+2] = fmaf(hk, w4.z, a[4*j+2]);
                    a[4*j+3] = fmaf(hk, w4.w, a[4*j+3]);
                }
            }

            // park upper half in LDS (same-lane DS ops are in-order: the
            // k<32 reads above complete before these overwrite)
            #pragma unroll
            for (int j = 0; j < 32; ++j)
                myact[j*64] = hh[j];

            // k = 32..63 from LDS (same sequential-k accumulation order)
            #pragma unroll 4
            for (int k = 32; k < DH; ++k) {
                const float hk = myact[(k-32)*64];
                const f32x4* wr = (const f32x4*)(Wl + k*DH);
                #pragma unroll
                for (int j = 0; j < 16; ++j) {
                    const f32x4 w4 = wr[j];
                    a[4*j+0] = fmaf(hk, w4.x, a[4*j+0]);
                    a[4*j+1] = fmaf(hk, w4.y, a[4*j+1]);
                    a[4*j+2] = fmaf(hk, w4.z, a[4*j+2]);
                    a[4*j+3] = fmaf(hk, w4.w, a[4*j+3]);
                }
            }
            const float* bm = b_mid + l*DH;
            #pragma unroll
            for (int d = 0; d < DH; ++d) a[d] += bm[d];
        }

        // ---- heads (4 chains each, identical to round 4)
        #pragma unroll
        for (int d = 0; d < DH; ++d) a[d] = fmaxf(a[d], 0.0f);

        float c0 = 0.f, c1 = 0.f, c2 = 0.f, c3 = 0.f;
        float e0 = 0.f, e1 = 0.f, e2 = 0.f, e3 = 0.f;
        #pragma unroll
        for (int j = 0; j < 16; ++j) {
            c0 = fmaf(a[4*j+0], W_cls[4*j+0],  c0);
            c1 = fmaf(a[4*j+1], W_cls[4*j+1],  c1);
            c2 = fmaf(a[4*j+2], W_cls[4*j+2],  c2);
            c3 = fmaf(a[4*j+3], W_cls[4*j+3],  c3);
            e0 = fmaf(a[4*j+0], W_dist[4*j+0], e0);
            e1 = fmaf(a[4*j+1], W_dist[4*j+1], e1);
            e2 = fmaf(a[4*j+2], W_dist[4*j+2], e2);
            e3 = fmaf(a[4*j+3], W_dist[4*j+3], e3);
        }
        float cls = ((c0 + c1) + (c2 + c3)) + b_cls[0];
        float dv  = ((e0 + e1) + (e2 + e3)) + b_dist[0];

        float dval = fmaf(dv, dt, t1i);

        // ---- amplification-aware borderline detection (identical)
        float thr = 2e-6f * invprod;
        thr = fminf(fmaxf(thr, 3e-5f), 2e-2f);
        const bool risky = (fabsf(cls) < thr) || (fabsf(dval) < thr);
        if (risky) {
            slow_eval(o0, o1, o2, v0, v1, v2, t1i, t2i,
                      W_in, b_in, ln_g, ln_b, W_mid, b_mid,
                      W_cls, b_cls, W_dist, b_dist, cls, dval);
        }

        if (cls > 0.0f && dval < dist) dist = dval;
    }

    const float dfin = (dist == BIGV) ? 0.0f : dist;
    out[r]     = (dfin > 0.0f) ? 1.0f : 0.0f;
    out[R + r] = dfin;
}

extern "C" void kernel_launch(void* const* d_in, const int* in_sizes, int n_in,
                              void* d_out, int out_size, void* d_ws, size_t ws_size,
                              hipStream_t stream) {
    const float* orig   = (const float*)d_in[0];
    const float* vec    = (const float*)d_in[1];
    const float* t1     = (const float*)d_in[2];
    const float* t2     = (const float*)d_in[3];
    const int*   mask   = (const int*)  d_in[4];
    const float* W_in   = (const float*)d_in[5];
    const float* b_in   = (const float*)d_in[6];
    const float* ln_g   = (const float*)d_in[7];
    const float* ln_b   = (const float*)d_in[8];
    const float* W_mid  = (const float*)d_in[9];
    const float* b_mid  = (const float*)d_in[10];
    const float* W_cls  = (const float*)d_in[11];
    const float* b_cls  = (const float*)d_in[12];
    const float* W_dist = (const float*)d_in[13];
    const float* b_dist = (const float*)d_in[14];

    float* out = (float*)d_out;
    const int R = in_sizes[0] / 3;

    const int threads = 256;
    const int blocks  = (R + threads - 1) / threads;
    nbvh_fused<<<blocks, threads, 0, stream>>>(
        orig, vec, t1, t2, mask,
        W_in, b_in, ln_g, ln_b, W_mid, b_mid,
        W_cls, b_cls, W_dist, b_dist,
        out, R);
}